// Round 1
// baseline (1331.693 us; speedup 1.0000x reference)
//
#include <hip/hip_runtime.h>
#include <math.h>

#define E_    8
#define TOPK_ 2
#define HID_  1024
#define FFN_  2048
#define M_    2048   // B*S = 2*1024

// ---------------------------------------------------------------------------
// Router: one block (1 wave) per token. 8 dot products of length 1024,
// butterfly reduce, softmax, top-2. Writes ids/wts to ws, topk_w to out tail,
// and atomically counts tokens per expert.
// ---------------------------------------------------------------------------
__global__ __launch_bounds__(64) void router_kernel(
    const float* __restrict__ x, const float* __restrict__ rw,
    const float* __restrict__ rb, int* __restrict__ ids,
    float* __restrict__ wts, int* __restrict__ cnt,
    float* __restrict__ topk_out)
{
    const int m    = blockIdx.x;
    const int lane = threadIdx.x;
    const float* xm = x + (size_t)m * HID_;

    float lg[E_];
#pragma unroll
    for (int e = 0; e < E_; ++e) {
        const float* we = rw + e * HID_;
        float s = 0.f;
        for (int k = lane; k < HID_; k += 64) s = fmaf(xm[k], we[k], s);
        lg[e] = s;
    }
#pragma unroll
    for (int off = 32; off; off >>= 1)
#pragma unroll
        for (int e = 0; e < E_; ++e) lg[e] += __shfl_xor(lg[e], off);

    if (lane == 0) {
        float l2[E_], p[E_];
        float mx = -1e30f;
#pragma unroll
        for (int e = 0; e < E_; ++e) { l2[e] = lg[e] + rb[e]; mx = fmaxf(mx, l2[e]); }
        float sum = 0.f;
#pragma unroll
        for (int e = 0; e < E_; ++e) { p[e] = expf(l2[e] - mx); sum += p[e]; }
        float inv = 1.f / sum;
#pragma unroll
        for (int e = 0; e < E_; ++e) p[e] *= inv;

        // top-2, ties -> lower index first (matches jax.lax.top_k)
        int   i1 = -1, i2 = -1;
        float v1 = -1e30f, v2 = -1e30f;
#pragma unroll
        for (int e = 0; e < E_; ++e) {
            float pe = p[e];
            if (pe > v1)      { v2 = v1; i2 = i1; v1 = pe; i1 = e; }
            else if (pe > v2) { v2 = pe; i2 = e; }
        }
        ids[2*m]   = i1;  ids[2*m+1]   = i2;
        wts[2*m]   = v1;  wts[2*m+1]   = v2;
        topk_out[2*m]   = v1;
        topk_out[2*m+1] = v2;
        atomicAdd(&cnt[i1], 1);
        atomicAdd(&cnt[i2], 1);
    }
}

// ---------------------------------------------------------------------------
// Exclusive prefix sum over E=8 counts (single thread; trivial).
// ---------------------------------------------------------------------------
__global__ void offsets_kernel(const int* __restrict__ cnt,
                               int* __restrict__ off, int* __restrict__ fill)
{
    if (threadIdx.x == 0 && blockIdx.x == 0) {
        int acc = 0;
        for (int e = 0; e < E_; ++e) { off[e] = acc; fill[e] = acc; acc += cnt[e]; }
    }
}

// ---------------------------------------------------------------------------
// Scatter tokens into compact per-expert lists.
// ---------------------------------------------------------------------------
__global__ __launch_bounds__(256) void scatter_kernel(
    const int* __restrict__ ids, const float* __restrict__ wts,
    int* __restrict__ fill, int* __restrict__ gtok, float* __restrict__ gwt)
{
    int m = blockIdx.x * 256 + threadIdx.x;
    if (m >= M_) return;
#pragma unroll
    for (int s = 0; s < TOPK_; ++s) {
        int e = ids[2*m + s];
        int p = atomicAdd(&fill[e], 1);
        gtok[p] = m;
        gwt[p]  = wts[2*m + s];
    }
}

// ---------------------------------------------------------------------------
// GEMM1 + SiLU*up. Per block: 64 gathered tokens x 128 ffn outputs
// (256 gu columns: gate + up). 256 threads, 8x8 micro-tile, K-step 16.
// h[p][n] = silu(x@w1_gate + b) * (x@w1_up + b)
// ---------------------------------------------------------------------------
__global__ __launch_bounds__(256) void gemm1_kernel(
    const float* __restrict__ x,  const float* __restrict__ w1,
    const float* __restrict__ w1b, const int* __restrict__ gtok,
    const int* __restrict__ cnt,  const int* __restrict__ off,
    float* __restrict__ h)
{
    const int e  = blockIdx.z;
    const int ce = cnt[e];
    const int t0 = blockIdx.y * 64;
    if (t0 >= ce) return;
    const int n0   = blockIdx.x * 128;
    const int base = off[e];
    const float* w1e = w1 + (size_t)e * (2*FFN_) * HID_;

    __shared__ float xs [16][64];
    __shared__ float wsm[16][256];

    const int tid = threadIdx.x;
    const int tt  = tid >> 5;   // 0..7 : token group (8 tokens)
    const int tc  = tid & 31;   // 0..31: col group  (4 gate + 4 up)

    float accg[8][4] = {}, accu[8][4] = {};

    const int xlr = tid >> 2;   // 0..63 row for x staging
    const int xkc = tid & 3;    // float4 chunk
    const bool xok = (t0 + xlr < ce);
    const float* xrow = xok ? (x + (size_t)gtok[base + t0 + xlr] * HID_) : nullptr;

    for (int k0 = 0; k0 < HID_; k0 += 16) {
        float4 xv = make_float4(0.f, 0.f, 0.f, 0.f);
        if (xrow) xv = *(const float4*)(xrow + k0 + xkc*4);
        float4 wv[4];
#pragma unroll
        for (int q = 0; q < 4; ++q) {
            int row  = (tid >> 2) + q*64;            // 0..255
            int grow = (row < 128) ? (n0 + row) : (FFN_ + n0 + row - 128);
            wv[q] = *(const float4*)(w1e + (size_t)grow*HID_ + k0 + (tid&3)*4);
        }
        __syncthreads();
        xs[xkc*4+0][xlr] = xv.x; xs[xkc*4+1][xlr] = xv.y;
        xs[xkc*4+2][xlr] = xv.z; xs[xkc*4+3][xlr] = xv.w;
#pragma unroll
        for (int q = 0; q < 4; ++q) {
            int row = (tid >> 2) + q*64;
            int kc  = tid & 3;
            wsm[kc*4+0][row] = wv[q].x; wsm[kc*4+1][row] = wv[q].y;
            wsm[kc*4+2][row] = wv[q].z; wsm[kc*4+3][row] = wv[q].w;
        }
        __syncthreads();
#pragma unroll
        for (int kk = 0; kk < 16; ++kk) {
            float a[8];
            *(float4*)&a[0] = *(const float4*)&xs[kk][tt*8];
            *(float4*)&a[4] = *(const float4*)&xs[kk][tt*8 + 4];
            float bg[4], bu[4];
            *(float4*)bg = *(const float4*)&wsm[kk][tc*4];
            *(float4*)bu = *(const float4*)&wsm[kk][128 + tc*4];
#pragma unroll
            for (int i = 0; i < 8; ++i)
#pragma unroll
                for (int j = 0; j < 4; ++j) {
                    accg[i][j] = fmaf(a[i], bg[j], accg[i][j]);
                    accu[i][j] = fmaf(a[i], bu[j], accu[i][j]);
                }
        }
    }

    float bgb[4], bub[4];
#pragma unroll
    for (int j = 0; j < 4; ++j) {
        bgb[j] = w1b[e*2*FFN_ + n0 + tc*4 + j];
        bub[j] = w1b[e*2*FFN_ + FFN_ + n0 + tc*4 + j];
    }
#pragma unroll
    for (int i = 0; i < 8; ++i) {
        int t = t0 + tt*8 + i;
        if (t < ce) {
            size_t p = (size_t)base + t;
            float4 hv;
            float* hvp = &hv.x;
#pragma unroll
            for (int j = 0; j < 4; ++j) {
                float g = accg[i][j] + bgb[j];
                float u = accu[i][j] + bub[j];
                hvp[j] = (g / (1.f + expf(-g))) * u;
            }
            *(float4*)(h + p*FFN_ + n0 + tc*4) = hv;
        }
    }
}

// ---------------------------------------------------------------------------
// GEMM2 + weighted combine. Per block: 64 pairs x 256 hid outputs.
// out[tok][c] += gwt[p] * (h[p] @ w2[e][c] + w2b[e][c])   (atomicAdd; exactly
// 2 addends per output + exact 0 init -> commutative -> deterministic)
// ---------------------------------------------------------------------------
__global__ __launch_bounds__(256) void gemm2_kernel(
    const float* __restrict__ h,   const float* __restrict__ w2,
    const float* __restrict__ w2b, const int* __restrict__ gtok,
    const float* __restrict__ gwt, const int* __restrict__ cnt,
    const int* __restrict__ off,   float* __restrict__ out)
{
    const int e  = blockIdx.z;
    const int ce = cnt[e];
    const int t0 = blockIdx.y * 64;
    if (t0 >= ce) return;
    const int c0   = blockIdx.x * 256;    // HID/256 = 4 tiles
    const int base = off[e];
    const float* w2e = w2 + (size_t)e * HID_ * FFN_;

    __shared__ float hs [16][64];
    __shared__ float wsm[16][256];

    const int tid = threadIdx.x;
    const int tt  = tid >> 5;
    const int tc  = tid & 31;

    float acc0[8][4] = {}, acc1[8][4] = {};

    const int xlr = tid >> 2;
    const int xkc = tid & 3;
    const bool xok = (t0 + xlr < ce);
    const float* hrow = h + (size_t)(base + t0 + xlr) * FFN_;

    for (int k0 = 0; k0 < FFN_; k0 += 16) {
        float4 hv = make_float4(0.f, 0.f, 0.f, 0.f);
        if (xok) hv = *(const float4*)(hrow + k0 + xkc*4);
        float4 wv[4];
#pragma unroll
        for (int q = 0; q < 4; ++q) {
            int row = (tid >> 2) + q*64;
            wv[q] = *(const float4*)(w2e + (size_t)(c0 + row)*FFN_ + k0 + (tid&3)*4);
        }
        __syncthreads();
        hs[xkc*4+0][xlr] = hv.x; hs[xkc*4+1][xlr] = hv.y;
        hs[xkc*4+2][xlr] = hv.z; hs[xkc*4+3][xlr] = hv.w;
#pragma unroll
        for (int q = 0; q < 4; ++q) {
            int row = (tid >> 2) + q*64;
            int kc  = tid & 3;
            wsm[kc*4+0][row] = wv[q].x; wsm[kc*4+1][row] = wv[q].y;
            wsm[kc*4+2][row] = wv[q].z; wsm[kc*4+3][row] = wv[q].w;
        }
        __syncthreads();
#pragma unroll
        for (int kk = 0; kk < 16; ++kk) {
            float a[8];
            *(float4*)&a[0] = *(const float4*)&hs[kk][tt*8];
            *(float4*)&a[4] = *(const float4*)&hs[kk][tt*8 + 4];
            float b0[4], b1[4];
            *(float4*)b0 = *(const float4*)&wsm[kk][tc*4];
            *(float4*)b1 = *(const float4*)&wsm[kk][128 + tc*4];
#pragma unroll
            for (int i = 0; i < 8; ++i)
#pragma unroll
                for (int j = 0; j < 4; ++j) {
                    acc0[i][j] = fmaf(a[i], b0[j], acc0[i][j]);
                    acc1[i][j] = fmaf(a[i], b1[j], acc1[i][j]);
                }
        }
    }

#pragma unroll
    for (int i = 0; i < 8; ++i) {
        int t = t0 + tt*8 + i;
        if (t < ce) {
            size_t p = (size_t)base + t;
            int tok  = gtok[p];
            float w  = gwt[p];
            float* orow = out + (size_t)tok * HID_;
#pragma unroll
            for (int j = 0; j < 4; ++j) {
                int c1 = c0 + tc*4 + j;
                int c2 = c0 + 128 + tc*4 + j;
                atomicAdd(&orow[c1], w * (acc0[i][j] + w2b[e*HID_ + c1]));
                atomicAdd(&orow[c2], w * (acc1[i][j] + w2b[e*HID_ + c2]));
            }
        }
    }
}

// ---------------------------------------------------------------------------
extern "C" void kernel_launch(void* const* d_in, const int* in_sizes, int n_in,
                              void* d_out, int out_size, void* d_ws, size_t ws_size,
                              hipStream_t stream)
{
    const float* x   = (const float*)d_in[0];
    const float* rw  = (const float*)d_in[1];
    const float* rb  = (const float*)d_in[2];
    const float* w1  = (const float*)d_in[3];
    const float* w1b = (const float*)d_in[4];
    const float* w2  = (const float*)d_in[5];
    const float* w2b = (const float*)d_in[6];

    float* out      = (float*)d_out;
    float* topk_out = out + (size_t)M_ * HID_;   // second output, (M, 2)

    // ws layout (needs 128KB + 33.5MB)
    char*  ws   = (char*)d_ws;
    int*   ids  = (int*)  (ws);            // M*2 ints
    float* wts  = (float*)(ws + 16384);    // M*2 floats
    int*   gtok = (int*)  (ws + 32768);    // M*2 ints
    float* gwt  = (float*)(ws + 49152);    // M*2 floats
    int*   cnt  = (int*)  (ws + 65536);    // E
    int*   off  = (int*)  (ws + 65536 + 128);
    int*   fill = (int*)  (ws + 65536 + 256);
    float* h    = (float*)(ws + 131072);   // M*2 * FFN floats = 33.5 MB

    hipMemsetAsync(cnt, 0, E_ * sizeof(int), stream);
    hipMemsetAsync(out, 0, (size_t)M_ * HID_ * sizeof(float), stream);

    router_kernel<<<M_, 64, 0, stream>>>(x, rw, rb, ids, wts, cnt, topk_out);
    offsets_kernel<<<1, 64, 0, stream>>>(cnt, off, fill);
    scatter_kernel<<<M_/256, 256, 0, stream>>>(ids, wts, fill, gtok, gwt);

    dim3 g1(FFN_/128, M_/64, E_);   // (16, 32, 8)
    gemm1_kernel<<<g1, 256, 0, stream>>>(x, w1, w1b, gtok, cnt, off, h);

    dim3 g2(HID_/256, M_/64, E_);   // (4, 32, 8)
    gemm2_kernel<<<g2, 256, 0, stream>>>(h, w2, w2b, gtok, gwt, cnt, off, out);
}

// Round 2
// 323.050 us; speedup vs baseline: 4.1222x; 4.1222x over previous
//
#include <hip/hip_runtime.h>
#include <hip/hip_bf16.h>
#include <math.h>

#define E_    8
#define HID_  1024
#define FFN_  2048
#define M_    2048     // B*S
#define NP_   (M_*2)   // total (token, expert) pairs

typedef __attribute__((ext_vector_type(8))) short bf16x8;
typedef __attribute__((ext_vector_type(4))) float f32x4;

typedef const __attribute__((address_space(1))) void GVOID;
typedef __attribute__((address_space(3))) void LVOID;

__device__ __forceinline__ short f2bf(float f) {
    union { __hip_bfloat16 b; short s; } u;
    u.b = __float2bfloat16(f);
    return u.s;
}

// ---------------------------------------------------------------------------
// x (fp32) -> xb (bf16), 2M elements
// ---------------------------------------------------------------------------
__global__ __launch_bounds__(256) void convert_x_kernel(
    const float* __restrict__ x, __hip_bfloat16* __restrict__ xb)
{
    int i = (blockIdx.x * 256 + threadIdx.x) * 4;
    float4 v = *(const float4*)(x + i);
    short4 o;
    o.x = f2bf(v.x); o.y = f2bf(v.y); o.z = f2bf(v.z); o.w = f2bf(v.w);
    *(short4*)((short*)xb + i) = o;
}

// ---------------------------------------------------------------------------
// Router: one wave per token (unchanged from passing round-1 version)
// ---------------------------------------------------------------------------
__global__ __launch_bounds__(64) void router_kernel(
    const float* __restrict__ x, const float* __restrict__ rw,
    const float* __restrict__ rb, int* __restrict__ ids,
    float* __restrict__ wts, int* __restrict__ cnt,
    float* __restrict__ topk_out)
{
    const int m    = blockIdx.x;
    const int lane = threadIdx.x;
    const float* xm = x + (size_t)m * HID_;

    float lg[E_];
#pragma unroll
    for (int e = 0; e < E_; ++e) {
        const float* we = rw + e * HID_;
        float s = 0.f;
        for (int k = lane; k < HID_; k += 64) s = fmaf(xm[k], we[k], s);
        lg[e] = s;
    }
#pragma unroll
    for (int off = 32; off; off >>= 1)
#pragma unroll
        for (int e = 0; e < E_; ++e) lg[e] += __shfl_xor(lg[e], off);

    if (lane == 0) {
        float l2[E_], p[E_];
        float mx = -1e30f;
#pragma unroll
        for (int e = 0; e < E_; ++e) { l2[e] = lg[e] + rb[e]; mx = fmaxf(mx, l2[e]); }
        float sum = 0.f;
#pragma unroll
        for (int e = 0; e < E_; ++e) { p[e] = expf(l2[e] - mx); sum += p[e]; }
        float inv = 1.f / sum;
#pragma unroll
        for (int e = 0; e < E_; ++e) p[e] *= inv;

        int   i1 = -1, i2 = -1;
        float v1 = -1e30f, v2 = -1e30f;
#pragma unroll
        for (int e = 0; e < E_; ++e) {
            float pe = p[e];
            if (pe > v1)      { v2 = v1; i2 = i1; v1 = pe; i1 = e; }
            else if (pe > v2) { v2 = pe; i2 = e; }
        }
        ids[2*m]   = i1;  ids[2*m+1]   = i2;
        wts[2*m]   = v1;  wts[2*m+1]   = v2;
        topk_out[2*m]   = v1;
        topk_out[2*m+1] = v2;
        atomicAdd(&cnt[i1], 1);
        atomicAdd(&cnt[i2], 1);
    }
}

__global__ void offsets_kernel(const int* __restrict__ cnt,
                               int* __restrict__ off, int* __restrict__ fill)
{
    if (threadIdx.x == 0 && blockIdx.x == 0) {
        int acc = 0;
        for (int e = 0; e < E_; ++e) { off[e] = acc; fill[e] = acc; acc += cnt[e]; }
    }
}

__global__ __launch_bounds__(256) void scatter_kernel(
    const int* __restrict__ ids, const float* __restrict__ wts,
    int* __restrict__ fill, int* __restrict__ gtok, float* __restrict__ gwt)
{
    int m = blockIdx.x * 256 + threadIdx.x;
    if (m >= M_) return;
#pragma unroll
    for (int s = 0; s < 2; ++s) {
        int e = ids[2*m + s];
        int p = atomicAdd(&fill[e], 1);
        gtok[p] = m;
        gwt[p]  = wts[2*m + s];
    }
}

// ---------------------------------------------------------------------------
// GEMM1 (MFMA bf16): per block 128 gathered tokens x 64 h-cols.
// B-tile rows (128): [0:32)=gate[n0..+32) [32:64)=up[n0..+32)
//                    [64:96)=gate[n0+32..+64) [96:128)=up[n0+32..+64)
// A via global_load_lds from xb (swizzled source), B reg-staged fp32->bf16.
// ---------------------------------------------------------------------------
__global__ __launch_bounds__(256) void gemm1_kernel(
    const __hip_bfloat16* __restrict__ xb, const float* __restrict__ w1,
    const float* __restrict__ w1b, const int* __restrict__ gtok,
    const int* __restrict__ cnt, const int* __restrict__ off,
    __hip_bfloat16* __restrict__ h)
{
    const int e  = blockIdx.z;
    const int ce = cnt[e];
    const int t0 = blockIdx.y * 128;
    if (t0 >= ce) return;
    const int n0   = blockIdx.x * 64;
    const int base = off[e];
    const float* w1e = w1 + (size_t)e * (2*FFN_) * HID_;

    __shared__ __align__(16) __hip_bfloat16 As[128*64];
    __shared__ __align__(16) __hip_bfloat16 Bs[128*64];

    const int tid  = threadIdx.x;
    const int lane = tid & 63;
    const int wid  = tid >> 6;
    const int wm   = wid >> 1;
    const int wn   = wid & 1;

    // A-staging per-lane source addresses (4 slots of 16B per thread)
    const __hip_bfloat16* asrc[4];
#pragma unroll
    for (int q = 0; q < 4; ++q) {
        int slot = q*256 + tid;
        int r = slot >> 3, p = slot & 7;
        int rr  = min(t0 + r, ce - 1);
        int tok = gtok[base + rr];
        int c = p ^ (r & 7);               // inverse-swizzled source chunk
        asrc[q] = xb + (size_t)tok * HID_ + c*8;
    }

    // B-staging mapping: thread -> (row, k-half)
    const int brow = tid >> 1;
    const int hk   = tid & 1;
    const int q2 = brow >> 5, s = brow & 31;
    const int grow = (q2 & 1) ? (FFN_ + n0 + (q2>>1)*32 + s)
                              : (       n0 + (q2>>1)*32 + s);
    const float* bsrc = w1e + (size_t)grow * HID_ + hk*32;

    f32x4 acc[4][4];
#pragma unroll
    for (int m = 0; m < 4; ++m)
#pragma unroll
        for (int n = 0; n < 4; ++n) acc[m][n] = (f32x4){0.f,0.f,0.f,0.f};

    float4 breg[8];
#pragma unroll
    for (int j = 0; j < 8; ++j) breg[j] = *(const float4*)(bsrc + j*4);

    for (int k0 = 0; k0 < HID_; k0 += 64) {
        // A -> LDS (async, linear dest)
#pragma unroll
        for (int q = 0; q < 4; ++q) {
            __builtin_amdgcn_global_load_lds(
                (GVOID*)(asrc[q] + k0),
                (LVOID*)(As + (q*256 + wid*64)*8),
                16, 0, 0);
        }
        // B: cvt fp32->bf16, swizzled ds_write_b128
#pragma unroll
        for (int cc = 0; cc < 4; ++cc) {
            union { bf16x8 v; short s8[8]; } u;
            const float* f0 = (const float*)&breg[2*cc];
#pragma unroll
            for (int j = 0; j < 8; ++j) u.s8[j] = f2bf(f0[j]);
            int c = hk*4 + cc, p = c ^ (brow & 7);
            *(bf16x8*)&Bs[brow*64 + p*8] = u.v;
        }
        __syncthreads();

        if (k0 + 64 < HID_) {
#pragma unroll
            for (int j = 0; j < 8; ++j) breg[j] = *(const float4*)(bsrc + (k0+64) + j*4);
        }

        bf16x8 af[4][2], bfr[4][2];
#pragma unroll
        for (int m = 0; m < 4; ++m)
#pragma unroll
            for (int kk = 0; kk < 2; ++kk) {
                int r = wm*64 + m*16 + (lane & 15);
                int c = kk*4 + (lane >> 4), p = c ^ (r & 7);
                af[m][kk] = *(bf16x8*)&As[r*64 + p*8];
            }
#pragma unroll
        for (int n = 0; n < 4; ++n)
#pragma unroll
            for (int kk = 0; kk < 2; ++kk) {
                int r = wn*64 + n*16 + (lane & 15);
                int c = kk*4 + (lane >> 4), p = c ^ (r & 7);
                bfr[n][kk] = *(bf16x8*)&Bs[r*64 + p*8];
            }
#pragma unroll
        for (int kk = 0; kk < 2; ++kk)
#pragma unroll
            for (int m = 0; m < 4; ++m)
#pragma unroll
                for (int n = 0; n < 4; ++n)
                    acc[m][n] = __builtin_amdgcn_mfma_f32_16x16x32_bf16(
                        af[m][kk], bfr[n][kk], acc[m][n], 0, 0, 0);
        __syncthreads();
    }

    // Epilogue: fused SiLU(gate)*up -> h (bf16)
    const float* w1be = w1b + e*2*FFN_;
#pragma unroll
    for (int n = 0; n < 2; ++n) {
        int col = n0 + wn*32 + n*16 + (lane & 15);
        float bg = w1be[col];
        float bu = w1be[FFN_ + col];
#pragma unroll
        for (int m = 0; m < 4; ++m) {
            int rb2 = t0 + wm*64 + m*16 + (lane >> 4)*4;
#pragma unroll
            for (int i = 0; i < 4; ++i) {
                int t = rb2 + i;
                if (t < ce) {
                    float g = acc[m][n][i]   + bg;
                    float u = acc[m][n+2][i] + bu;
                    float hv = (g / (1.f + __expf(-g))) * u;
                    h[(size_t)(base + t)*FFN_ + col] = __float2bfloat16(hv);
                }
            }
        }
    }
}

// ---------------------------------------------------------------------------
// GEMM2 (MFMA bf16): per block 128 pairs x 128 hid cols; weighted atomic
// combine into out (exactly 2 commutative addends per element).
// ---------------------------------------------------------------------------
__global__ __launch_bounds__(256) void gemm2_kernel(
    const __hip_bfloat16* __restrict__ h, const float* __restrict__ w2,
    const float* __restrict__ w2b, const int* __restrict__ gtok,
    const float* __restrict__ gwt, const int* __restrict__ cnt,
    const int* __restrict__ off, float* __restrict__ out)
{
    const int e  = blockIdx.z;
    const int ce = cnt[e];
    const int t0 = blockIdx.y * 128;
    if (t0 >= ce) return;
    const int n0   = blockIdx.x * 128;
    const int base = off[e];
    const float* w2e = w2 + (size_t)e * HID_ * FFN_;

    __shared__ __align__(16) __hip_bfloat16 As[128*64];
    __shared__ __align__(16) __hip_bfloat16 Bs[128*64];

    const int tid  = threadIdx.x;
    const int lane = tid & 63;
    const int wid  = tid >> 6;
    const int wm   = wid >> 1;
    const int wn   = wid & 1;

    const __hip_bfloat16* asrc[4];
#pragma unroll
    for (int q = 0; q < 4; ++q) {
        int slot = q*256 + tid;
        int r = slot >> 3, p = slot & 7;
        int rr = min(t0 + r, ce - 1);
        int c = p ^ (r & 7);
        asrc[q] = h + (size_t)(base + rr) * FFN_ + c*8;
    }

    const int brow = tid >> 1;
    const int hk   = tid & 1;
    const float* bsrc = w2e + (size_t)(n0 + brow) * FFN_ + hk*32;

    f32x4 acc[4][4];
#pragma unroll
    for (int m = 0; m < 4; ++m)
#pragma unroll
        for (int n = 0; n < 4; ++n) acc[m][n] = (f32x4){0.f,0.f,0.f,0.f};

    float4 breg[8];
#pragma unroll
    for (int j = 0; j < 8; ++j) breg[j] = *(const float4*)(bsrc + j*4);

    for (int k0 = 0; k0 < FFN_; k0 += 64) {
#pragma unroll
        for (int q = 0; q < 4; ++q) {
            __builtin_amdgcn_global_load_lds(
                (GVOID*)(asrc[q] + k0),
                (LVOID*)(As + (q*256 + wid*64)*8),
                16, 0, 0);
        }
#pragma unroll
        for (int cc = 0; cc < 4; ++cc) {
            union { bf16x8 v; short s8[8]; } u;
            const float* f0 = (const float*)&breg[2*cc];
#pragma unroll
            for (int j = 0; j < 8; ++j) u.s8[j] = f2bf(f0[j]);
            int c = hk*4 + cc, p = c ^ (brow & 7);
            *(bf16x8*)&Bs[brow*64 + p*8] = u.v;
        }
        __syncthreads();

        if (k0 + 64 < FFN_) {
#pragma unroll
            for (int j = 0; j < 8; ++j) breg[j] = *(const float4*)(bsrc + (k0+64) + j*4);
        }

        bf16x8 af[4][2], bfr[4][2];
#pragma unroll
        for (int m = 0; m < 4; ++m)
#pragma unroll
            for (int kk = 0; kk < 2; ++kk) {
                int r = wm*64 + m*16 + (lane & 15);
                int c = kk*4 + (lane >> 4), p = c ^ (r & 7);
                af[m][kk] = *(bf16x8*)&As[r*64 + p*8];
            }
#pragma unroll
        for (int n = 0; n < 4; ++n)
#pragma unroll
            for (int kk = 0; kk < 2; ++kk) {
                int r = wn*64 + n*16 + (lane & 15);
                int c = kk*4 + (lane >> 4), p = c ^ (r & 7);
                bfr[n][kk] = *(bf16x8*)&Bs[r*64 + p*8];
            }
#pragma unroll
        for (int kk = 0; kk < 2; ++kk)
#pragma unroll
            for (int m = 0; m < 4; ++m)
#pragma unroll
                for (int n = 0; n < 4; ++n)
                    acc[m][n] = __builtin_amdgcn_mfma_f32_16x16x32_bf16(
                        af[m][kk], bfr[n][kk], acc[m][n], 0, 0, 0);
        __syncthreads();
    }

    const float* w2be = w2b + e*HID_;
#pragma unroll
    for (int n = 0; n < 4; ++n) {
        int col = n0 + wn*64 + n*16 + (lane & 15);
        float bias = w2be[col];
#pragma unroll
        for (int m = 0; m < 4; ++m) {
            int rb2 = t0 + wm*64 + m*16 + (lane >> 4)*4;
#pragma unroll
            for (int i = 0; i < 4; ++i) {
                int t = rb2 + i;
                if (t < ce) {
                    int p  = base + t;
                    int tok = gtok[p];
                    float w = gwt[p];
                    atomicAdd(&out[(size_t)tok*HID_ + col], w * (acc[m][n][i] + bias));
                }
            }
        }
    }
}

// ---------------------------------------------------------------------------
extern "C" void kernel_launch(void* const* d_in, const int* in_sizes, int n_in,
                              void* d_out, int out_size, void* d_ws, size_t ws_size,
                              hipStream_t stream)
{
    const float* x   = (const float*)d_in[0];
    const float* rw  = (const float*)d_in[1];
    const float* rb  = (const float*)d_in[2];
    const float* w1  = (const float*)d_in[3];
    const float* w1b = (const float*)d_in[4];
    const float* w2  = (const float*)d_in[5];
    const float* w2b = (const float*)d_in[6];

    float* out      = (float*)d_out;
    float* topk_out = out + (size_t)M_ * HID_;

    char*  ws   = (char*)d_ws;
    int*   ids  = (int*)  (ws);
    float* wts  = (float*)(ws + 16384);
    int*   gtok = (int*)  (ws + 32768);
    float* gwt  = (float*)(ws + 49152);
    int*   cnt  = (int*)  (ws + 65536);
    int*   off  = (int*)  (ws + 65536 + 128);
    int*   fill = (int*)  (ws + 65536 + 256);
    __hip_bfloat16* xb = (__hip_bfloat16*)(ws + 131072);                    // 4 MB
    __hip_bfloat16* h  = (__hip_bfloat16*)(ws + 131072 + 4*1024*1024);      // 16 MB

    hipMemsetAsync(cnt, 0, E_ * sizeof(int), stream);
    hipMemsetAsync(out, 0, (size_t)M_ * HID_ * sizeof(float), stream);

    convert_x_kernel<<<(M_*HID_)/(256*4), 256, 0, stream>>>(x, xb);
    router_kernel<<<M_, 64, 0, stream>>>(x, rw, rb, ids, wts, cnt, topk_out);
    offsets_kernel<<<1, 64, 0, stream>>>(cnt, off, fill);
    scatter_kernel<<<M_/256, 256, 0, stream>>>(ids, wts, fill, gtok, gwt);

    dim3 g1(FFN_/64, M_/128, E_);    // (32, 16, 8)
    gemm1_kernel<<<g1, 256, 0, stream>>>(xb, w1, w1b, gtok, cnt, off, h);

    dim3 g2(HID_/128, M_/128, E_);   // (8, 16, 8)
    gemm2_kernel<<<g2, 256, 0, stream>>>(h, w2, w2b, gtok, gwt, cnt, off, out);
}